// Round 1
// baseline (3572.052 us; speedup 1.0000x reference)
//
#include <hip/hip_runtime.h>
#include <hip/hip_bf16.h>

#define GH 52
#define GW 92
#define BP 19136
#define HP 364
#define WP 644
#define HIN 360
#define WIN_ 640

__device__ __constant__ float c_mean[3] = {114.444f, 111.4605f, 103.02f};

// workspace layout (bytes)
#define OFF_FEAT2 0ULL            // fp32 BP x 576   (44.1 MB)  -- dead after GEMM
#define OFF_Y64   0ULL            // bf16 4x64x364x644 (120 MB) -- aliases feat2 (conv3 runs after GEMM)
#define OFF_KB    120020992ULL    // fp32 BP x 896   (68.6 MB)
#define OFF_Y32   188604416ULL    // bf16 4x32x364x644 (60 MB)
#define OFF_W2T   248614912ULL    // fp32 576x64
#define OFF_W3T   248762368ULL    // fp32 800x64
#define OFF_W4T   248967168ULL    // fp32 576x12
#define WS_NEED   248994816ULL

// ---------------- prep: weight transposes for contiguous/uniform inner-loop reads ----------
__global__ __launch_bounds__(256) void k_prep(const float* __restrict__ w2, float* __restrict__ w2t,
                                              const float* __restrict__ w3, float* __restrict__ w3t,
                                              const float* __restrict__ w4, float* __restrict__ w4t)
{
    int i = blockIdx.x * 256 + threadIdx.x;
    if (i < 36864) { int oc = i / 576, k = i % 576; w2t[k*64 + oc] = w2[i]; }
    if (i < 51200) { int oc = i / 800, r = i % 800; w3t[r*64 + oc] = w3[i]; }
    if (i < 6912)  { int o  = i / 576, r = i % 576; w4t[r*12 + o]  = w4[i]; }
}

// ---------------- head: patch extract + conv1(3->64,7->5) + conv2(64->64,5->3) -------------
__global__ __launch_bounds__(192) void k_head(
    const float* __restrict__ x, const float* __restrict__ w1, const float* __restrict__ b1,
    const float* __restrict__ w2t, const float* __restrict__ b2, float* __restrict__ feat2)
{
    __shared__ float sp[8][148];    // 8 patches, 3*7*7 each
    __shared__ float sf[8][1601];   // feat1: 64*5*5 per patch (+1 pad vs 32 banks)
    const int tid = threadIdx.x;
    const int p0 = blockIdx.x * 8;

    for (int t = tid; t < 8*147; t += 192) {
        int p = t / 147, r = t % 147;
        int c = r / 49, rr = r % 49;
        int i = rr / 7, j = rr % 7;
        int pg = p0 + p;
        int b = pg / (GH*GW), rem = pg % (GH*GW);
        int gy = rem / GW, gx = rem % GW;
        int yy = gy*7 + i, xx = gx*7 + j;
        float v = 0.f;
        if (yy < HIN && xx < WIN_) v = x[((b*3 + c)*HIN + yy)*WIN_ + xx] - c_mean[c];
        sp[p][r] = v;
    }
    __syncthreads();

    // conv1: 8 patches * 64oc * 25pos
    for (int t = tid; t < 8*1600; t += 192) {
        int p = t / 1600, r = t % 1600;
        int oc = r / 25, pos = r % 25;
        int pi = pos / 5, pj = pos % 5;
        float acc = b1[oc];
        const float* wp = w1 + oc*27;
        #pragma unroll
        for (int c = 0; c < 3; ++c)
            #pragma unroll
            for (int ki = 0; ki < 3; ++ki)
                #pragma unroll
                for (int kj = 0; kj < 3; ++kj)
                    acc += sp[p][c*49 + (pi+ki)*7 + (pj+kj)] * wp[c*9 + ki*3 + kj];
        sf[p][oc*25 + pos] = fmaxf(acc, 0.f);
    }
    __syncthreads();

    // conv2: tasks = 8 ocg * 8 patches * 9 pos = 576 = 3*192 (perfect balance)
    for (int t = tid; t < 576; t += 192) {
        int ocg = t / 72, rem = t % 72;
        int p = rem / 9, pos = rem % 9;
        int pi = pos / 3, pj = pos % 3;
        float acc[8];
        #pragma unroll
        for (int u = 0; u < 8; ++u) acc[u] = b2[ocg*8 + u];
        for (int c = 0; c < 64; ++c) {
            const float* fb = &sf[p][c*25];
            #pragma unroll
            for (int ki = 0; ki < 3; ++ki)
                #pragma unroll
                for (int kj = 0; kj < 3; ++kj) {
                    float fv = fb[(pi+ki)*5 + (pj+kj)];
                    const float* wr = w2t + (c*9 + ki*3 + kj)*64 + ocg*8;
                    const float4 wa = *reinterpret_cast<const float4*>(wr);
                    const float4 wb4 = *reinterpret_cast<const float4*>(wr + 4);
                    acc[0] += fv*wa.x;  acc[1] += fv*wa.y;  acc[2] += fv*wa.z;  acc[3] += fv*wa.w;
                    acc[4] += fv*wb4.x; acc[5] += fv*wb4.y; acc[6] += fv*wb4.z; acc[7] += fv*wb4.w;
                }
        }
        float* o = feat2 + (size_t)(p0 + p)*576;
        #pragma unroll
        for (int u = 0; u < 8; ++u)
            o[(ocg*8 + u)*9 + pos] = fmaxf(acc[u], 0.f);  // layout [oc][pos] = im2col K order
    }
}

// ---------------- GEMM: kern+bias = feat2 @ [wk|wb]^T ;  M=19136 N=896 K=576 ---------------
__global__ __launch_bounds__(256) void k_gemm(
    const float* __restrict__ feat2, const float* __restrict__ wk, const float* __restrict__ bk,
    const float* __restrict__ wb, const float* __restrict__ bb, float* __restrict__ kb)
{
    __shared__ __align__(16) float As[16][68];
    __shared__ __align__(16) float Bs[16][68];
    const int tid = threadIdx.x;
    const int tx = tid & 15, ty = tid >> 4;
    const int m0 = blockIdx.x * 64, n0 = blockIdx.y * 64;
    float acc[4][4] = {};

    const int row = tid >> 2;            // 0..63
    const int kq  = (tid & 3) * 4;       // 0,4,8,12
    const int nb  = n0 + row;
    const float* bsrc = (nb < 864) ? (wk + (size_t)nb*576) : (wb + (size_t)(nb-864)*576);
    const float* asrc = feat2 + (size_t)(m0 + row)*576;

    for (int k0 = 0; k0 < 576; k0 += 16) {
        float4 a4 = *reinterpret_cast<const float4*>(asrc + k0 + kq);
        float4 b4 = *reinterpret_cast<const float4*>(bsrc + k0 + kq);
        As[kq+0][row] = a4.x; As[kq+1][row] = a4.y; As[kq+2][row] = a4.z; As[kq+3][row] = a4.w;
        Bs[kq+0][row] = b4.x; Bs[kq+1][row] = b4.y; Bs[kq+2][row] = b4.z; Bs[kq+3][row] = b4.w;
        __syncthreads();
        #pragma unroll
        for (int kk = 0; kk < 16; ++kk) {
            float4 a = *reinterpret_cast<const float4*>(&As[kk][ty*4]);
            float4 b = *reinterpret_cast<const float4*>(&Bs[kk][tx*4]);
            float av[4] = {a.x, a.y, a.z, a.w};
            float bv[4] = {b.x, b.y, b.z, b.w};
            #pragma unroll
            for (int i = 0; i < 4; ++i)
                #pragma unroll
                for (int j = 0; j < 4; ++j)
                    acc[i][j] += av[i] * bv[j];
        }
        __syncthreads();
    }
    #pragma unroll
    for (int i = 0; i < 4; ++i) {
        int m = m0 + ty*4 + i;
        #pragma unroll
        for (int j = 0; j < 4; ++j) {
            int n = n0 + tx*4 + j;
            float bias = (n < 864) ? bk[n] : bb[n - 864];
            kb[(size_t)m*896 + n] = acc[i][j] + bias;
        }
    }
}

// ---------------- apply predicted 3x3x3->32 kernel per patch, assemble y32 -----------------
__global__ __launch_bounds__(256) void k_apply(
    const float* __restrict__ x, const float* __restrict__ kb, __hip_bfloat16* __restrict__ y32)
{
    __shared__ float pp[3][9][9];     // zero-padded patch
    __shared__ __align__(16) float kl[27][32];    // kern transposed [k][f]
    __shared__ float bl[32];
    const int p = blockIdx.x;
    const int tid = threadIdx.x;
    const int b = p / (GH*GW), rem = p % (GH*GW);
    const int gy = rem / GW, gx = rem % GW;

    for (int t = tid; t < 243; t += 256) ((float*)pp)[t] = 0.f;
    __syncthreads();
    for (int t = tid; t < 147; t += 256) {
        int c = t / 49, r = t % 49, i = r / 7, j = r % 7;
        int yy = gy*7 + i, xx = gx*7 + j;
        float v = 0.f;
        if (yy < HIN && xx < WIN_) v = x[((b*3 + c)*HIN + yy)*WIN_ + xx] - c_mean[c];
        pp[c][i+1][j+1] = v;
    }
    for (int t = tid; t < 864; t += 256) {
        int f = t / 27, k = t % 27;
        kl[k][f] = kb[(size_t)p*896 + t];
    }
    if (tid < 32) bl[tid] = kb[(size_t)p*896 + 864 + tid];
    __syncthreads();

    if (tid < 196) {
        int pos = tid % 49, fg = tid / 49;     // fg in 0..3 (8 f each)
        int h = pos / 7, w = pos % 7;
        float win[27];
        #pragma unroll
        for (int c = 0; c < 3; ++c)
            #pragma unroll
            for (int i = 0; i < 3; ++i)
                #pragma unroll
                for (int j = 0; j < 3; ++j)
                    win[c*9 + i*3 + j] = pp[c][h+i][w+j];
        float acc[8];
        #pragma unroll
        for (int u = 0; u < 8; ++u) acc[u] = bl[fg*8 + u];
        #pragma unroll
        for (int k = 0; k < 27; ++k) {
            const float4 wa = *reinterpret_cast<const float4*>(&kl[k][fg*8]);
            const float4 wb4 = *reinterpret_cast<const float4*>(&kl[k][fg*8 + 4]);
            float v = win[k];
            acc[0] += v*wa.x;  acc[1] += v*wa.y;  acc[2] += v*wa.z;  acc[3] += v*wa.w;
            acc[4] += v*wb4.x; acc[5] += v*wb4.y; acc[6] += v*wb4.z; acc[7] += v*wb4.w;
        }
        int yy = gy*7 + h, xx = gx*7 + w;
        #pragma unroll
        for (int u = 0; u < 8; ++u) {
            int f = fg*8 + u;
            y32[((size_t)(b*32 + f)*HP + yy)*WP + xx] = __float2bfloat16(acc[u]);
        }
    }
}

// ---------------- conv3: 32->64 5x5 pad2 + relu, over 364x644 ------------------------------
__global__ __launch_bounds__(256) void k_conv3(
    const __hip_bfloat16* __restrict__ y32, const float* __restrict__ w3t,
    const float* __restrict__ b3, __hip_bfloat16* __restrict__ y64)
{
    __shared__ float sin_[32][20][20];   // 51.2 KB
    const int tid = threadIdx.x;
    const int x0 = blockIdx.x * 16, y0 = blockIdx.y * 16, b = blockIdx.z;

    for (int t = tid; t < 32*400; t += 256) {
        int c = t / 400, r = t % 400;
        int iy = r / 20, ix = r % 20;
        int yy = y0 + iy - 2, xx = x0 + ix - 2;
        float v = 0.f;
        if (yy >= 0 && yy < HP && xx >= 0 && xx < WP)
            v = __bfloat162float(y32[((size_t)(b*32 + c)*HP + yy)*WP + xx]);
        sin_[c][iy][ix] = v;
    }
    __syncthreads();

    const int px = tid & 15, py = tid >> 4;
    const int ox = x0 + px, oy = y0 + py;
    const bool valid = (ox < WP) && (oy < HP);
    for (int ocg = 0; ocg < 8; ++ocg) {
        float acc[8];
        #pragma unroll
        for (int u = 0; u < 8; ++u) acc[u] = b3[ocg*8 + u];
        for (int c = 0; c < 32; ++c) {
            #pragma unroll
            for (int ky = 0; ky < 5; ++ky)
                #pragma unroll
                for (int kx = 0; kx < 5; ++kx) {
                    float v = sin_[c][py + ky][px + kx];
                    const float* wr = w3t + (c*25 + ky*5 + kx)*64 + ocg*8;
                    const float4 wa = *reinterpret_cast<const float4*>(wr);
                    const float4 wb4 = *reinterpret_cast<const float4*>(wr + 4);
                    acc[0] += v*wa.x;  acc[1] += v*wa.y;  acc[2] += v*wa.z;  acc[3] += v*wa.w;
                    acc[4] += v*wb4.x; acc[5] += v*wb4.y; acc[6] += v*wb4.z; acc[7] += v*wb4.w;
                }
        }
        if (valid) {
            #pragma unroll
            for (int u = 0; u < 8; ++u)
                y64[((size_t)(b*64 + ocg*8 + u)*HP + oy)*WP + ox] = __float2bfloat16(fmaxf(acc[u], 0.f));
        }
    }
}

// ---------------- conv4: 64->12 3x3 pad1 + pixel-shuffle x2 + mean add ---------------------
__global__ __launch_bounds__(256) void k_conv4(
    const __hip_bfloat16* __restrict__ y64, const float* __restrict__ w4t,
    const float* __restrict__ b4, float* __restrict__ out)
{
    __shared__ __hip_bfloat16 sin_[64][18][18];  // 41.5 KB
    const int tid = threadIdx.x;
    const int x0 = blockIdx.x * 16, y0 = blockIdx.y * 16, b = blockIdx.z;

    for (int t = tid; t < 64*324; t += 256) {
        int c = t / 324, r = t % 324;
        int iy = r / 18, ix = r % 18;
        int yy = y0 + iy - 1, xx = x0 + ix - 1;
        __hip_bfloat16 v = __float2bfloat16(0.f);
        if (yy >= 0 && yy < HP && xx >= 0 && xx < WP)
            v = y64[((size_t)(b*64 + c)*HP + yy)*WP + xx];
        sin_[c][iy][ix] = v;
    }
    __syncthreads();

    const int px = tid & 15, py = tid >> 4;
    const int ox = x0 + px, oy = y0 + py;
    const bool valid = (ox < WIN_) && (oy < HIN);
    float acc[12];
    #pragma unroll
    for (int o = 0; o < 12; ++o) acc[o] = b4[o];
    for (int c = 0; c < 64; ++c) {
        #pragma unroll
        for (int ky = 0; ky < 3; ++ky)
            #pragma unroll
            for (int kx = 0; kx < 3; ++kx) {
                float v = __bfloat162float(sin_[c][py + ky][px + kx]);
                const float* wr = w4t + (c*9 + ky*3 + kx)*12;
                #pragma unroll
                for (int o = 0; o < 12; ++o) acc[o] += v * wr[o];
            }
    }
    if (valid) {
        #pragma unroll
        for (int co = 0; co < 3; ++co)
            #pragma unroll
            for (int sy = 0; sy < 2; ++sy)
                #pragma unroll
                for (int sx = 0; sx < 2; ++sx)
                    out[((size_t)(b*3 + co)*720 + oy*2 + sy)*1280 + ox*2 + sx]
                        = acc[co*4 + sy*2 + sx] + c_mean[co];
    }
}

extern "C" void kernel_launch(void* const* d_in, const int* in_sizes, int n_in,
                              void* d_out, int out_size, void* d_ws, size_t ws_size,
                              hipStream_t stream) {
    const float* x  = (const float*)d_in[0];
    const float* w1 = (const float*)d_in[1];
    const float* b1 = (const float*)d_in[2];
    const float* w2 = (const float*)d_in[3];
    const float* b2 = (const float*)d_in[4];
    const float* wk = (const float*)d_in[5];
    const float* bk = (const float*)d_in[6];
    const float* wb = (const float*)d_in[7];
    const float* bb = (const float*)d_in[8];
    const float* w3 = (const float*)d_in[9];
    const float* b3 = (const float*)d_in[10];
    const float* w4 = (const float*)d_in[11];
    const float* b4 = (const float*)d_in[12];
    float* out = (float*)d_out;

    if (ws_size < WS_NEED) return;  // workspace too small; bail rather than corrupt

    char* ws = (char*)d_ws;
    float* feat2 = (float*)(ws + OFF_FEAT2);
    float* kb    = (float*)(ws + OFF_KB);
    __hip_bfloat16* y32 = (__hip_bfloat16*)(ws + OFF_Y32);
    __hip_bfloat16* y64 = (__hip_bfloat16*)(ws + OFF_Y64);
    float* w2t = (float*)(ws + OFF_W2T);
    float* w3t = (float*)(ws + OFF_W3T);
    float* w4t = (float*)(ws + OFF_W4T);

    k_prep <<<200, 256, 0, stream>>>(w2, w2t, w3, w3t, w4, w4t);
    k_head <<<BP/8, 192, 0, stream>>>(x, w1, b1, w2t, b2, feat2);
    k_gemm <<<dim3(299, 14), 256, 0, stream>>>(feat2, wk, bk, wb, bb, kb);
    k_apply<<<BP, 256, 0, stream>>>(x, kb, y32);
    k_conv3<<<dim3(41, 23, 4), 256, 0, stream>>>(y32, w3t, b3, y64);
    k_conv4<<<dim3(40, 23, 4), 256, 0, stream>>>(y64, w4t, b4, out);
}

// Round 2
// 1408.693 us; speedup vs baseline: 2.5357x; 2.5357x over previous
//
#include <hip/hip_runtime.h>
#include <hip/hip_bf16.h>

#define GH 52
#define GW 92
#define BP 19136
#define HP 364
#define WP 644
#define HIN 360
#define WIN_ 640

typedef __attribute__((ext_vector_type(8))) short short8;
typedef __attribute__((ext_vector_type(4))) float f32x4;

__device__ __constant__ float c_mean[3] = {114.444f, 111.4605f, 103.02f};

// workspace layout (bytes)
#define OFF_FEAT2 0ULL            // fp32 BP x 576 (44.1 MB) -- dead after GEMM
#define OFF_Y64   0ULL            // bf16 NHWC 4x364x644x64 (120 MB) -- aliases feat2
#define OFF_KB    120020992ULL    // fp32 BP x 896 (68.6 MB)
#define OFF_Y32   188604416ULL    // bf16 NHWC 4x364x644x32 (60 MB)
#define OFF_W2T   248614912ULL    // fp32 576x64
#define OFF_W3B   248762368ULL    // bf16 [25tap][64oc][32c]
#define OFF_W4B   248864768ULL    // bf16 [9tap][2kh][16n][32c]
#define WS_NEED   248883200ULL

static __device__ __forceinline__ short bf16bits(float v) {
    __hip_bfloat16 h = __float2bfloat16(v);
    return *reinterpret_cast<short*>(&h);
}

// ---------------- prep: weight repacks ----------------------------------------------------
__global__ __launch_bounds__(256) void k_prep(const float* __restrict__ w2, float* __restrict__ w2t,
                                              const float* __restrict__ w3, short* __restrict__ w3b,
                                              const float* __restrict__ w4, short* __restrict__ w4b)
{
    int i = blockIdx.x * 256 + threadIdx.x;
    if (i < 36864) { int oc = i / 576, k = i % 576; w2t[k*64 + oc] = w2[i]; }
    if (i < 51200) {
        // i = (tap*64 + oc)*32 + c ;  w3 layout [oc][c][ky][kx]
        int c = i & 31; int rest = i >> 5; int oc = rest & 63; int tap = rest >> 6;
        int ky = tap / 5, kx = tap % 5;
        w3b[i] = bf16bits(w3[((oc*32 + c)*5 + ky)*5 + kx]);
    }
    if (i < 9216) {
        // i = ((tap*2+kh)*16 + n)*32 + c ; w4 layout [o][ic][ky][kx], pad n>=12 with 0
        int c = i & 31; int rest = i >> 5; int n = rest & 15; rest >>= 4;
        int kh = rest & 1; int tap = rest >> 1;
        int ky = tap / 3, kx = tap % 3;
        float v = 0.f;
        if (n < 12) v = w4[((n*64 + kh*32 + c)*3 + ky)*3 + kx];
        w4b[i] = bf16bits(v);
    }
}

// ---------------- head: patch extract + conv1(3->64,7->5) + conv2(64->64,5->3) -------------
__global__ __launch_bounds__(192) void k_head(
    const float* __restrict__ x, const float* __restrict__ w1, const float* __restrict__ b1,
    const float* __restrict__ w2t, const float* __restrict__ b2, float* __restrict__ feat2)
{
    __shared__ float sp[8][148];
    __shared__ float sf[8][1601];
    const int tid = threadIdx.x;
    const int p0 = blockIdx.x * 8;

    for (int t = tid; t < 8*147; t += 192) {
        int p = t / 147, r = t % 147;
        int c = r / 49, rr = r % 49;
        int i = rr / 7, j = rr % 7;
        int pg = p0 + p;
        int b = pg / (GH*GW), rem = pg % (GH*GW);
        int gy = rem / GW, gx = rem % GW;
        int yy = gy*7 + i, xx = gx*7 + j;
        float v = 0.f;
        if (yy < HIN && xx < WIN_) v = x[((b*3 + c)*HIN + yy)*WIN_ + xx] - c_mean[c];
        sp[p][r] = v;
    }
    __syncthreads();

    for (int t = tid; t < 8*1600; t += 192) {
        int p = t / 1600, r = t % 1600;
        int oc = r / 25, pos = r % 25;
        int pi = pos / 5, pj = pos % 5;
        float acc = b1[oc];
        const float* wp = w1 + oc*27;
        #pragma unroll
        for (int c = 0; c < 3; ++c)
            #pragma unroll
            for (int ki = 0; ki < 3; ++ki)
                #pragma unroll
                for (int kj = 0; kj < 3; ++kj)
                    acc += sp[p][c*49 + (pi+ki)*7 + (pj+kj)] * wp[c*9 + ki*3 + kj];
        sf[p][oc*25 + pos] = fmaxf(acc, 0.f);
    }
    __syncthreads();

    for (int t = tid; t < 576; t += 192) {
        int ocg = t / 72, rem = t % 72;
        int p = rem / 9, pos = rem % 9;
        int pi = pos / 3, pj = pos % 3;
        float acc[8];
        #pragma unroll
        for (int u = 0; u < 8; ++u) acc[u] = b2[ocg*8 + u];
        for (int c = 0; c < 64; ++c) {
            const float* fb = &sf[p][c*25];
            #pragma unroll
            for (int ki = 0; ki < 3; ++ki)
                #pragma unroll
                for (int kj = 0; kj < 3; ++kj) {
                    float fv = fb[(pi+ki)*5 + (pj+kj)];
                    const float* wr = w2t + (c*9 + ki*3 + kj)*64 + ocg*8;
                    const float4 wa = *reinterpret_cast<const float4*>(wr);
                    const float4 wb4 = *reinterpret_cast<const float4*>(wr + 4);
                    acc[0] += fv*wa.x;  acc[1] += fv*wa.y;  acc[2] += fv*wa.z;  acc[3] += fv*wa.w;
                    acc[4] += fv*wb4.x; acc[5] += fv*wb4.y; acc[6] += fv*wb4.z; acc[7] += fv*wb4.w;
                }
        }
        float* o = feat2 + (size_t)(p0 + p)*576;
        #pragma unroll
        for (int u = 0; u < 8; ++u)
            o[(ocg*8 + u)*9 + pos] = fmaxf(acc[u], 0.f);
    }
}

// ---------------- GEMM: kern+bias = feat2 @ [wk|wb]^T ;  M=19136 N=896 K=576 ---------------
__global__ __launch_bounds__(256) void k_gemm(
    const float* __restrict__ feat2, const float* __restrict__ wk, const float* __restrict__ bk,
    const float* __restrict__ wb, const float* __restrict__ bb, float* __restrict__ kb)
{
    __shared__ __align__(16) float As[16][68];
    __shared__ __align__(16) float Bs[16][68];
    const int tid = threadIdx.x;
    const int tx = tid & 15, ty = tid >> 4;
    const int m0 = blockIdx.x * 64, n0 = blockIdx.y * 64;
    float acc[4][4] = {};

    const int row = tid >> 2;
    const int kq  = (tid & 3) * 4;
    const int nb  = n0 + row;
    const float* bsrc = (nb < 864) ? (wk + (size_t)nb*576) : (wb + (size_t)(nb-864)*576);
    const float* asrc = feat2 + (size_t)(m0 + row)*576;

    for (int k0 = 0; k0 < 576; k0 += 16) {
        float4 a4 = *reinterpret_cast<const float4*>(asrc + k0 + kq);
        float4 b4 = *reinterpret_cast<const float4*>(bsrc + k0 + kq);
        As[kq+0][row] = a4.x; As[kq+1][row] = a4.y; As[kq+2][row] = a4.z; As[kq+3][row] = a4.w;
        Bs[kq+0][row] = b4.x; Bs[kq+1][row] = b4.y; Bs[kq+2][row] = b4.z; Bs[kq+3][row] = b4.w;
        __syncthreads();
        #pragma unroll
        for (int kk = 0; kk < 16; ++kk) {
            float4 a = *reinterpret_cast<const float4*>(&As[kk][ty*4]);
            float4 b = *reinterpret_cast<const float4*>(&Bs[kk][tx*4]);
            float av[4] = {a.x, a.y, a.z, a.w};
            float bv[4] = {b.x, b.y, b.z, b.w};
            #pragma unroll
            for (int i = 0; i < 4; ++i)
                #pragma unroll
                for (int j = 0; j < 4; ++j)
                    acc[i][j] += av[i] * bv[j];
        }
        __syncthreads();
    }
    #pragma unroll
    for (int i = 0; i < 4; ++i) {
        int m = m0 + ty*4 + i;
        #pragma unroll
        for (int j = 0; j < 4; ++j) {
            int n = n0 + tx*4 + j;
            float bias = (n < 864) ? bk[n] : bb[n - 864];
            kb[(size_t)m*896 + n] = acc[i][j] + bias;
        }
    }
}

// ---------------- apply predicted 3x3x3->32 kernel per patch -> y32 NHWC bf16 --------------
__global__ __launch_bounds__(256) void k_apply(
    const float* __restrict__ x, const float* __restrict__ kb, __hip_bfloat16* __restrict__ y32)
{
    __shared__ float pp[3][9][9];
    __shared__ __align__(16) float kl[27][32];
    __shared__ float bl[32];
    const int p = blockIdx.x;
    const int tid = threadIdx.x;
    const int b = p / (GH*GW), rem = p % (GH*GW);
    const int gy = rem / GW, gx = rem % GW;

    for (int t = tid; t < 243; t += 256) ((float*)pp)[t] = 0.f;
    __syncthreads();
    for (int t = tid; t < 147; t += 256) {
        int c = t / 49, r = t % 49, i = r / 7, j = r % 7;
        int yy = gy*7 + i, xx = gx*7 + j;
        float v = 0.f;
        if (yy < HIN && xx < WIN_) v = x[((b*3 + c)*HIN + yy)*WIN_ + xx] - c_mean[c];
        pp[c][i+1][j+1] = v;
    }
    for (int t = tid; t < 864; t += 256) {
        int f = t / 27, k = t % 27;
        kl[k][f] = kb[(size_t)p*896 + t];
    }
    if (tid < 32) bl[tid] = kb[(size_t)p*896 + 864 + tid];
    __syncthreads();

    if (tid < 196) {
        int pos = tid % 49, fg = tid / 49;
        int h = pos / 7, w = pos % 7;
        float win[27];
        #pragma unroll
        for (int c = 0; c < 3; ++c)
            #pragma unroll
            for (int i = 0; i < 3; ++i)
                #pragma unroll
                for (int j = 0; j < 3; ++j)
                    win[c*9 + i*3 + j] = pp[c][h+i][w+j];
        float acc[8];
        #pragma unroll
        for (int u = 0; u < 8; ++u) acc[u] = bl[fg*8 + u];
        #pragma unroll
        for (int k = 0; k < 27; ++k) {
            const float4 wa = *reinterpret_cast<const float4*>(&kl[k][fg*8]);
            const float4 wb4 = *reinterpret_cast<const float4*>(&kl[k][fg*8 + 4]);
            float v = win[k];
            acc[0] += v*wa.x;  acc[1] += v*wa.y;  acc[2] += v*wa.z;  acc[3] += v*wa.w;
            acc[4] += v*wb4.x; acc[5] += v*wb4.y; acc[6] += v*wb4.z; acc[7] += v*wb4.w;
        }
        int yy = gy*7 + h, xx = gx*7 + w;
        short8 pack;
        #pragma unroll
        for (int u = 0; u < 8; ++u) pack[u] = bf16bits(acc[u]);
        *reinterpret_cast<short8*>(
            reinterpret_cast<short*>(y32) + (((size_t)b*HP + yy)*WP + xx)*32 + fg*8) = pack;
    }
}

// ---------------- conv3 MFMA: NHWC 32->64, 5x5 pad2 + relu --------------------------------
// per-tap implicit GEMM: 25 taps x mfma_f32_16x16x32_bf16, tile 16x16 px, 4 waves
__global__ __launch_bounds__(256) void k_conv3(
    const __hip_bfloat16* __restrict__ y32, const short* __restrict__ w3b,
    const float* __restrict__ b3, __hip_bfloat16* __restrict__ y64)
{
    __shared__ __align__(16) short sin_[20*20*32];   // NHWC tile, 25.6 KB
    const int tid = threadIdx.x;
    const int x0 = blockIdx.x * 16, y0 = blockIdx.y * 16, b = blockIdx.z;

    for (int t = tid; t < 1600; t += 256) {          // 16B chunks
        int pix = t >> 2, q4 = t & 3;
        int iy = pix / 20, ix = pix % 20;
        int yy = y0 + iy - 2, xx = x0 + ix - 2;
        uint4 v = make_uint4(0u, 0u, 0u, 0u);
        if (yy >= 0 && yy < HP && xx >= 0 && xx < WP)
            v = *reinterpret_cast<const uint4*>(
                reinterpret_cast<const short*>(y32) + (((size_t)b*HP + yy)*WP + xx)*32 + q4*8);
        *reinterpret_cast<uint4*>(&sin_[pix*32 + q4*8]) = v;
    }
    __syncthreads();

    const int wv = tid >> 6;
    const int lane = tid & 63;
    const int n16 = lane & 15;
    const int q = lane >> 4;

    f32x4 acc[4][4];
    #pragma unroll
    for (int j = 0; j < 4; ++j) {
        float bv = b3[j*16 + n16];
        #pragma unroll
        for (int i = 0; i < 4; ++i) acc[i][j] = {bv, bv, bv, bv};
    }

    for (int ky = 0; ky < 5; ++ky) {
        for (int kx = 0; kx < 5; ++kx) {
            const int tap = ky*5 + kx;
            short8 bf[4];
            #pragma unroll
            for (int j = 0; j < 4; ++j)
                bf[j] = *reinterpret_cast<const short8*>(w3b + (tap*64 + j*16 + n16)*32 + q*8);
            short8 af[4];
            #pragma unroll
            for (int i = 0; i < 4; ++i) {
                int pix = (wv*4 + i + ky)*20 + (n16 + kx);
                af[i] = *reinterpret_cast<const short8*>(&sin_[pix*32 + q*8]);
            }
            #pragma unroll
            for (int i = 0; i < 4; ++i)
                #pragma unroll
                for (int j = 0; j < 4; ++j)
                    acc[i][j] = __builtin_amdgcn_mfma_f32_16x16x32_bf16(af[i], bf[j], acc[i][j], 0, 0, 0);
        }
    }

    // D: col(oc)=lane&15, row(pixel-x)=q*4+reg
    #pragma unroll
    for (int i = 0; i < 4; ++i) {
        int yy = y0 + wv*4 + i;
        if (yy >= HP) continue;
        #pragma unroll
        for (int j = 0; j < 4; ++j) {
            #pragma unroll
            for (int r = 0; r < 4; ++r) {
                int xx = x0 + q*4 + r;
                if (xx < WP)
                    y64[(((size_t)b*HP + yy)*WP + xx)*64 + j*16 + n16] =
                        __float2bfloat16(fmaxf(acc[i][j][r], 0.f));
            }
        }
    }
}

// ---------------- conv4 MFMA: NHWC 64->12(pad16) 3x3 pad1 + pixel-shuffle + mean -----------
__global__ __launch_bounds__(256) void k_conv4(
    const __hip_bfloat16* __restrict__ y64, const short* __restrict__ w4b,
    const float* __restrict__ b4, float* __restrict__ out)
{
    __shared__ __align__(16) short sin_[18*18*72];   // 72-short/pixel pad (36w = 4 mod 32)
    const int tid = threadIdx.x;
    const int x0 = blockIdx.x * 16, y0 = blockIdx.y * 16, b = blockIdx.z;

    for (int t = tid; t < 2592; t += 256) {          // 16B chunks, 8 per pixel
        int pix = t >> 3, sub = t & 7;
        int iy = pix / 18, ix = pix % 18;
        int yy = y0 + iy - 1, xx = x0 + ix - 1;
        uint4 v = make_uint4(0u, 0u, 0u, 0u);
        if (yy >= 0 && yy < HP && xx >= 0 && xx < WP)
            v = *reinterpret_cast<const uint4*>(
                reinterpret_cast<const short*>(y64) + (((size_t)b*HP + yy)*WP + xx)*64 + sub*8);
        *reinterpret_cast<uint4*>(&sin_[pix*72 + sub*8]) = v;
    }
    __syncthreads();

    const int wv = tid >> 6;
    const int lane = tid & 63;
    const int n16 = lane & 15;
    const int q = lane >> 4;

    f32x4 acc[4];
    {
        float bv = (n16 < 12) ? b4[n16] : 0.f;
        #pragma unroll
        for (int i = 0; i < 4; ++i) acc[i] = {bv, bv, bv, bv};
    }

    for (int ky = 0; ky < 3; ++ky) {
        for (int kx = 0; kx < 3; ++kx) {
            const int tap = ky*3 + kx;
            short8 bf0 = *reinterpret_cast<const short8*>(w4b + ((tap*2 + 0)*16 + n16)*32 + q*8);
            short8 bf1 = *reinterpret_cast<const short8*>(w4b + ((tap*2 + 1)*16 + n16)*32 + q*8);
            #pragma unroll
            for (int i = 0; i < 4; ++i) {
                int pix = (wv*4 + i + ky)*18 + (n16 + kx);
                short8 a0 = *reinterpret_cast<const short8*>(&sin_[pix*72 + q*8]);
                short8 a1 = *reinterpret_cast<const short8*>(&sin_[pix*72 + 32 + q*8]);
                acc[i] = __builtin_amdgcn_mfma_f32_16x16x32_bf16(a0, bf0, acc[i], 0, 0, 0);
                acc[i] = __builtin_amdgcn_mfma_f32_16x16x32_bf16(a1, bf1, acc[i], 0, 0, 0);
            }
        }
    }

    // D: col n=lane&15 -> (co,sy,sx); row m=q*4+reg -> pixel-x; fold pixel shuffle
    if (n16 < 12) {
        const int co = n16 >> 2, sy = (n16 >> 1) & 1, sx = n16 & 1;
        #pragma unroll
        for (int i = 0; i < 4; ++i) {
            int yy = y0 + wv*4 + i;
            if (yy >= HIN) continue;
            #pragma unroll
            for (int r = 0; r < 4; ++r) {
                int xx = x0 + q*4 + r;
                if (xx < WIN_)
                    out[((size_t)(b*3 + co)*720 + yy*2 + sy)*1280 + xx*2 + sx]
                        = acc[i][r] + c_mean[co];
            }
        }
    }
}

extern "C" void kernel_launch(void* const* d_in, const int* in_sizes, int n_in,
                              void* d_out, int out_size, void* d_ws, size_t ws_size,
                              hipStream_t stream) {
    const float* x  = (const float*)d_in[0];
    const float* w1 = (const float*)d_in[1];
    const float* b1 = (const float*)d_in[2];
    const float* w2 = (const float*)d_in[3];
    const float* b2 = (const float*)d_in[4];
    const float* wk = (const float*)d_in[5];
    const float* bk = (const float*)d_in[6];
    const float* wb = (const float*)d_in[7];
    const float* bb = (const float*)d_in[8];
    const float* w3 = (const float*)d_in[9];
    const float* b3 = (const float*)d_in[10];
    const float* w4 = (const float*)d_in[11];
    const float* b4 = (const float*)d_in[12];
    float* out = (float*)d_out;

    if (ws_size < WS_NEED) return;

    char* ws = (char*)d_ws;
    float* feat2 = (float*)(ws + OFF_FEAT2);
    float* kb    = (float*)(ws + OFF_KB);
    __hip_bfloat16* y32 = (__hip_bfloat16*)(ws + OFF_Y32);
    __hip_bfloat16* y64 = (__hip_bfloat16*)(ws + OFF_Y64);
    float* w2t = (float*)(ws + OFF_W2T);
    short* w3b = (short*)(ws + OFF_W3B);
    short* w4b = (short*)(ws + OFF_W4B);

    k_prep <<<200, 256, 0, stream>>>(w2, w2t, w3, w3b, w4, w4b);
    k_head <<<BP/8, 192, 0, stream>>>(x, w1, b1, w2t, b2, feat2);
    k_gemm <<<dim3(299, 14), 256, 0, stream>>>(feat2, wk, bk, wb, bb, kb);
    k_apply<<<BP, 256, 0, stream>>>(x, kb, y32);
    k_conv3<<<dim3(41, 23, 4), 256, 0, stream>>>(y32, w3b, b3, y64);
    k_conv4<<<dim3(40, 23, 4), 256, 0, stream>>>(y64, w4b, b4, out);
}

// Round 3
// 666.335 us; speedup vs baseline: 5.3607x; 2.1141x over previous
//
#include <hip/hip_runtime.h>
#include <hip/hip_bf16.h>

#define GH 52
#define GW 92
#define BP 19136
#define HP 364
#define WP 644
#define HIN 360
#define WIN_ 640

typedef __attribute__((ext_vector_type(8))) short short8;
typedef __attribute__((ext_vector_type(4))) float f32x4;

__device__ __constant__ float c_mean[3] = {114.444f, 111.4605f, 103.02f};

// workspace layout (bytes)
#define OFF_FEAT2 0ULL            // bf16 BP x 576 (22.0 MB) -- dead after GEMM
#define OFF_Y64   0ULL            // bf16 NHWC 4x364x644x64 (120.0 MB) -- aliases feat2+kb
#define OFF_KB    22044672ULL     // fp32 BP x 896 (68.6 MB) -- dead after apply
#define OFF_Y32   120020992ULL    // bf16 NHWC 4x364x644x32 (60.0 MB)
#define OFF_W1T   180031488ULL    // fp32 27x64
#define OFF_W2B   180038400ULL    // bf16 [9tap][64oc][64c]
#define OFF_WKB   180112128ULL    // bf16 [896n][576k]
#define OFF_W3B   181144320ULL    // bf16 [25tap][64oc][32c]
#define OFF_W4B   181246720ULL    // bf16 [9tap][2kh][16n][32c]
#define WS_NEED   181265152ULL

static __device__ __forceinline__ short bf16bits(float v) {
    __hip_bfloat16 h = __float2bfloat16(v);
    return *reinterpret_cast<short*>(&h);
}

// ---------------- prep: weight repacks ----------------------------------------------------
__global__ __launch_bounds__(256) void k_prep(
    const float* __restrict__ w1, float* __restrict__ w1t,
    const float* __restrict__ w2, short* __restrict__ w2b,
    const float* __restrict__ wk, const float* __restrict__ wb, short* __restrict__ wkb,
    const float* __restrict__ w3, short* __restrict__ w3b,
    const float* __restrict__ w4, short* __restrict__ w4b)
{
    int i = blockIdx.x * 256 + threadIdx.x;
    if (i < 1728) { int oc = i / 27, k = i % 27; w1t[k*64 + oc] = w1[i]; }
    if (i < 36864) {
        // i = (tap*64 + oc)*64 + c ; w2 layout [oc][c][3][3]
        int c = i & 63; int rest = i >> 6; int oc = rest & 63; int tap = rest >> 6;
        int ky = tap / 3, kx = tap % 3;
        w2b[i] = bf16bits(w2[((oc*64 + c)*3 + ky)*3 + kx]);
    }
    if (i < 516096) {
        // i = n*576 + k ; wk flat = [n][f][ky][kx] = n*576 + (f*9+tap) -- identical K order
        int n = i / 576, k = i % 576;
        float v = (n < 864) ? wk[i] : wb[(n - 864)*576 + k];
        wkb[i] = bf16bits(v);
    }
    if (i < 51200) {
        // i = (tap*64 + oc)*32 + c ; w3 layout [oc][c][5][5]
        int c = i & 31; int rest = i >> 5; int oc = rest & 63; int tap = rest >> 6;
        int ky = tap / 5, kx = tap % 5;
        w3b[i] = bf16bits(w3[((oc*32 + c)*5 + ky)*5 + kx]);
    }
    if (i < 9216) {
        // i = ((tap*2+kh)*16 + n)*32 + c ; w4 layout [o][ic][3][3], pad n>=12 with 0
        int c = i & 31; int rest = i >> 5; int n = rest & 15; rest >>= 4;
        int kh = rest & 1; int tap = rest >> 1;
        int ky = tap / 3, kx = tap % 3;
        float v = 0.f;
        if (n < 12) v = w4[((n*64 + kh*32 + c)*3 + ky)*3 + kx];
        w4b[i] = bf16bits(v);
    }
}

// ---------------- head: 16 patches/block; conv1 VALU -> feat1 NHWC bf16 LDS;
//                  conv2 per-tap MFMA (M=144=16p x 9pos, N=64, K=576) -> feat2 bf16 --------
__global__ __launch_bounds__(256) void k_head(
    const float* __restrict__ x, const float* __restrict__ w1t, const float* __restrict__ b1,
    const short* __restrict__ w2b, const float* __restrict__ b2, short* __restrict__ feat2)
{
    __shared__ __hip_bfloat16 sp[16][148];          // input patches, bf16 (4.7 KB)
    __shared__ __align__(16) short sf1[16*25*72];   // feat1 NHWC, 72-short pixel stride (57.6 KB)
    const int tid = threadIdx.x;
    const int p0 = blockIdx.x * 16;

    // stage input patches
    for (int t = tid; t < 16*147; t += 256) {
        int p = t / 147, r = t % 147;
        int c = r / 49, rr = r % 49;
        int i = rr / 7, j = rr % 7;
        int pg = p0 + p;
        int b = pg / (GH*GW), rem = pg % (GH*GW);
        int gy = rem / GW, gx = rem % GW;
        int yy = gy*7 + i, xx = gx*7 + j;
        float v = 0.f;
        if (yy < HIN && xx < WIN_) v = x[((b*3 + c)*HIN + yy)*WIN_ + xx] - c_mean[c];
        sp[p][r] = __float2bfloat16(v);
    }
    __syncthreads();

    // conv1: tasks = 16p x 25pos x 8ocg, each computes 8 oc
    for (int t = tid; t < 3200; t += 256) {
        int p = t / 200, rem = t % 200;
        int pos = rem >> 3, ocg = rem & 7;
        int pi = pos / 5, pj = pos % 5;
        float acc[8];
        #pragma unroll
        for (int u = 0; u < 8; ++u) acc[u] = b1[ocg*8 + u];
        #pragma unroll
        for (int c = 0; c < 3; ++c)
            #pragma unroll
            for (int ki = 0; ki < 3; ++ki)
                #pragma unroll
                for (int kj = 0; kj < 3; ++kj) {
                    float fv = __bfloat162float(sp[p][c*49 + (pi+ki)*7 + (pj+kj)]);
                    const float* wr = w1t + (c*9 + ki*3 + kj)*64 + ocg*8;
                    const float4 wa = *reinterpret_cast<const float4*>(wr);
                    const float4 wb4 = *reinterpret_cast<const float4*>(wr + 4);
                    acc[0] += fv*wa.x;  acc[1] += fv*wa.y;  acc[2] += fv*wa.z;  acc[3] += fv*wa.w;
                    acc[4] += fv*wb4.x; acc[5] += fv*wb4.y; acc[6] += fv*wb4.z; acc[7] += fv*wb4.w;
                }
        short8 pack;
        #pragma unroll
        for (int u = 0; u < 8; ++u) pack[u] = bf16bits(fmaxf(acc[u], 0.f));
        *reinterpret_cast<short8*>(&sf1[(p*25 + pos)*72 + ocg*8]) = pack;
    }
    __syncthreads();

    // conv2 MFMA: waves split M-tiles {wv, wv+4, wv+8}; each wave does all 4 N-tiles
    const int wv = tid >> 6;
    const int lane = tid & 63;
    const int n16 = lane & 15;
    const int q = lane >> 4;

    int base[3]; int nmt = 0;
    #pragma unroll
    for (int s = 0; s < 3; ++s) {
        int mt = wv + s*4;
        if (mt < 9) {
            int m = mt*16 + n16;
            int pa = m / 9, po = m % 9;
            int pi = po / 3, pj = po % 3;
            base[s] = (pa*25 + pi*5 + pj)*72 + q*8;
            nmt = s + 1;
        }
    }

    f32x4 acc[3][4];
    #pragma unroll
    for (int nt = 0; nt < 4; ++nt) {
        float bv = b2[nt*16 + n16];
        #pragma unroll
        for (int s = 0; s < 3; ++s) acc[s][nt] = {bv, bv, bv, bv};
    }

    for (int ki = 0; ki < 3; ++ki)
        for (int kj = 0; kj < 3; ++kj) {
            const int tap = ki*3 + kj;
            const int off = (ki*5 + kj)*72;
            short8 bf[4][2];
            #pragma unroll
            for (int nt = 0; nt < 4; ++nt) {
                bf[nt][0] = *reinterpret_cast<const short8*>(w2b + (tap*64 + nt*16 + n16)*64 + q*8);
                bf[nt][1] = *reinterpret_cast<const short8*>(w2b + (tap*64 + nt*16 + n16)*64 + 32 + q*8);
            }
            for (int s = 0; s < nmt; ++s) {
                short8 a0 = *reinterpret_cast<const short8*>(&sf1[base[s] + off]);
                short8 a1 = *reinterpret_cast<const short8*>(&sf1[base[s] + off + 32]);
                #pragma unroll
                for (int nt = 0; nt < 4; ++nt) {
                    acc[s][nt] = __builtin_amdgcn_mfma_f32_16x16x32_bf16(a0, bf[nt][0], acc[s][nt], 0, 0, 0);
                    acc[s][nt] = __builtin_amdgcn_mfma_f32_16x16x32_bf16(a1, bf[nt][1], acc[s][nt], 0, 0, 0);
                }
            }
        }

    // store feat2: D col=n16 (oc within tile), row=q*4+r; feat2[p][oc*9+pos], relu
    for (int s = 0; s < nmt; ++s) {
        int mt = wv + s*4;
        #pragma unroll
        for (int nt = 0; nt < 4; ++nt) {
            int oc = nt*16 + n16;
            #pragma unroll
            for (int r = 0; r < 4; ++r) {
                int m = mt*16 + q*4 + r;
                int pa = m / 9, po = m % 9;
                feat2[(size_t)(p0 + pa)*576 + oc*9 + po] = bf16bits(fmaxf(acc[s][nt][r], 0.f));
            }
        }
    }
}

// ---------------- GEMM MFMA: kb = feat2(bf16) @ wkb^T + bias ; M=19136 N=896 K=576 ---------
__global__ __launch_bounds__(256) void k_gemm(
    const short* __restrict__ feat2, const short* __restrict__ wkb,
    const float* __restrict__ bk, const float* __restrict__ bb, float* __restrict__ kb)
{
    __shared__ __align__(16) short As[128*40];   // 128 rows x 32k, stride 40 (10 KB)
    __shared__ __align__(16) short Bs[128*40];
    const int tid = threadIdx.x;
    const int m0 = blockIdx.x * 128, n0 = blockIdx.y * 128;
    const int wv = tid >> 6, lane = tid & 63;
    const int n16 = lane & 15, q = lane >> 4;
    const int wm = wv & 1, wn = wv >> 1;

    f32x4 acc[4][4] = {};

    for (int k0 = 0; k0 < 576; k0 += 32) {
        for (int t = tid; t < 512; t += 256) {
            int row = t >> 2, seg = t & 3;
            uint4 a = *reinterpret_cast<const uint4*>(feat2 + (size_t)(m0 + row)*576 + k0 + seg*8);
            uint4 b = *reinterpret_cast<const uint4*>(wkb   + (size_t)(n0 + row)*576 + k0 + seg*8);
            *reinterpret_cast<uint4*>(&As[row*40 + seg*8]) = a;
            *reinterpret_cast<uint4*>(&Bs[row*40 + seg*8]) = b;
        }
        __syncthreads();
        short8 af[4], bf[4];
        #pragma unroll
        for (int mt = 0; mt < 4; ++mt)
            af[mt] = *reinterpret_cast<const short8*>(&As[(wm*64 + mt*16 + n16)*40 + q*8]);
        #pragma unroll
        for (int nt = 0; nt < 4; ++nt)
            bf[nt] = *reinterpret_cast<const short8*>(&Bs[(wn*64 + nt*16 + n16)*40 + q*8]);
        #pragma unroll
        for (int mt = 0; mt < 4; ++mt)
            #pragma unroll
            for (int nt = 0; nt < 4; ++nt)
                acc[mt][nt] = __builtin_amdgcn_mfma_f32_16x16x32_bf16(af[mt], bf[nt], acc[mt][nt], 0, 0, 0);
        __syncthreads();
    }

    #pragma unroll
    for (int nt = 0; nt < 4; ++nt) {
        int n = n0 + wn*64 + nt*16 + n16;
        float bias = (n < 864) ? bk[n] : bb[n - 864];
        #pragma unroll
        for (int mt = 0; mt < 4; ++mt)
            #pragma unroll
            for (int r = 0; r < 4; ++r) {
                int m = m0 + wm*64 + mt*16 + q*4 + r;
                if (m < BP) kb[(size_t)m*896 + n] = acc[mt][nt][r] + bias;
            }
    }
}

// ---------------- apply predicted 3x3x3->32 kernel per patch -> y32 NHWC bf16 --------------
__global__ __launch_bounds__(256) void k_apply(
    const float* __restrict__ x, const float* __restrict__ kb, __hip_bfloat16* __restrict__ y32)
{
    __shared__ float pp[3][9][9];
    __shared__ __align__(16) float kl[27][32];
    __shared__ float bl[32];
    const int p = blockIdx.x;
    const int tid = threadIdx.x;
    const int b = p / (GH*GW), rem = p % (GH*GW);
    const int gy = rem / GW, gx = rem % GW;

    for (int t = tid; t < 243; t += 256) ((float*)pp)[t] = 0.f;
    __syncthreads();
    for (int t = tid; t < 147; t += 256) {
        int c = t / 49, r = t % 49, i = r / 7, j = r % 7;
        int yy = gy*7 + i, xx = gx*7 + j;
        float v = 0.f;
        if (yy < HIN && xx < WIN_) v = x[((b*3 + c)*HIN + yy)*WIN_ + xx] - c_mean[c];
        pp[c][i+1][j+1] = v;
    }
    for (int t = tid; t < 864; t += 256) {
        int f = t / 27, k = t % 27;
        kl[k][f] = kb[(size_t)p*896 + t];
    }
    if (tid < 32) bl[tid] = kb[(size_t)p*896 + 864 + tid];
    __syncthreads();

    if (tid < 196) {
        int pos = tid % 49, fg = tid / 49;
        int h = pos / 7, w = pos % 7;
        float win[27];
        #pragma unroll
        for (int c = 0; c < 3; ++c)
            #pragma unroll
            for (int i = 0; i < 3; ++i)
                #pragma unroll
                for (int j = 0; j < 3; ++j)
                    win[c*9 + i*3 + j] = pp[c][h+i][w+j];
        float acc[8];
        #pragma unroll
        for (int u = 0; u < 8; ++u) acc[u] = bl[fg*8 + u];
        #pragma unroll
        for (int k = 0; k < 27; ++k) {
            const float4 wa = *reinterpret_cast<const float4*>(&kl[k][fg*8]);
            const float4 wb4 = *reinterpret_cast<const float4*>(&kl[k][fg*8 + 4]);
            float v = win[k];
            acc[0] += v*wa.x;  acc[1] += v*wa.y;  acc[2] += v*wa.z;  acc[3] += v*wa.w;
            acc[4] += v*wb4.x; acc[5] += v*wb4.y; acc[6] += v*wb4.z; acc[7] += v*wb4.w;
        }
        int yy = gy*7 + h, xx = gx*7 + w;
        short8 pack;
        #pragma unroll
        for (int u = 0; u < 8; ++u) pack[u] = bf16bits(acc[u]);
        *reinterpret_cast<short8*>(
            reinterpret_cast<short*>(y32) + (((size_t)b*HP + yy)*WP + xx)*32 + fg*8) = pack;
    }
}

// ---------------- conv3 MFMA: NHWC 32->64, 5x5 pad2 + relu --------------------------------
__global__ __launch_bounds__(256) void k_conv3(
    const __hip_bfloat16* __restrict__ y32, const short* __restrict__ w3b,
    const float* __restrict__ b3, __hip_bfloat16* __restrict__ y64)
{
    __shared__ __align__(16) short sin_[20*20*40];   // pixel stride 40 shorts (32 KB)
    const int tid = threadIdx.x;
    const int x0 = blockIdx.x * 16, y0 = blockIdx.y * 16, b = blockIdx.z;

    for (int t = tid; t < 1600; t += 256) {
        int pix = t >> 2, q4 = t & 3;
        int iy = pix / 20, ix = pix % 20;
        int yy = y0 + iy - 2, xx = x0 + ix - 2;
        uint4 v = make_uint4(0u, 0u, 0u, 0u);
        if (yy >= 0 && yy < HP && xx >= 0 && xx < WP)
            v = *reinterpret_cast<const uint4*>(
                reinterpret_cast<const short*>(y32) + (((size_t)b*HP + yy)*WP + xx)*32 + q4*8);
        *reinterpret_cast<uint4*>(&sin_[pix*40 + q4*8]) = v;
    }
    __syncthreads();

    const int wv = tid >> 6;
    const int lane = tid & 63;
    const int n16 = lane & 15;
    const int q = lane >> 4;

    f32x4 acc[4][4];
    #pragma unroll
    for (int j = 0; j < 4; ++j) {
        float bv = b3[j*16 + n16];
        #pragma unroll
        for (int i = 0; i < 4; ++i) acc[i][j] = {bv, bv, bv, bv};
    }

    for (int ky = 0; ky < 5; ++ky) {
        for (int kx = 0; kx < 5; ++kx) {
            const int tap = ky*5 + kx;
            short8 bf[4];
            #pragma unroll
            for (int j = 0; j < 4; ++j)
                bf[j] = *reinterpret_cast<const short8*>(w3b + (tap*64 + j*16 + n16)*32 + q*8);
            short8 af[4];
            #pragma unroll
            for (int i = 0; i < 4; ++i) {
                int pix = (wv*4 + i + ky)*20 + (n16 + kx);
                af[i] = *reinterpret_cast<const short8*>(&sin_[pix*40 + q*8]);
            }
            #pragma unroll
            for (int i = 0; i < 4; ++i)
                #pragma unroll
                for (int j = 0; j < 4; ++j)
                    acc[i][j] = __builtin_amdgcn_mfma_f32_16x16x32_bf16(af[i], bf[j], acc[i][j], 0, 0, 0);
        }
    }

    #pragma unroll
    for (int i = 0; i < 4; ++i) {
        int yy = y0 + wv*4 + i;
        if (yy >= HP) continue;
        #pragma unroll
        for (int j = 0; j < 4; ++j) {
            #pragma unroll
            for (int r = 0; r < 4; ++r) {
                int xx = x0 + q*4 + r;
                if (xx < WP)
                    y64[(((size_t)b*HP + yy)*WP + xx)*64 + j*16 + n16] =
                        __float2bfloat16(fmaxf(acc[i][j][r], 0.f));
            }
        }
    }
}

// ---------------- conv4 MFMA: NHWC 64->12(pad16) 3x3 pad1 + pixel-shuffle + mean -----------
__global__ __launch_bounds__(256) void k_conv4(
    const __hip_bfloat16* __restrict__ y64, const short* __restrict__ w4b,
    const float* __restrict__ b4, float* __restrict__ out)
{
    __shared__ __align__(16) short sin_[18*18*72];
    const int tid = threadIdx.x;
    const int x0 = blockIdx.x * 16, y0 = blockIdx.y * 16, b = blockIdx.z;

    for (int t = tid; t < 2592; t += 256) {
        int pix = t >> 3, sub = t & 7;
        int iy = pix / 18, ix = pix % 18;
        int yy = y0 + iy - 1, xx = x0 + ix - 1;
        uint4 v = make_uint4(0u, 0u, 0u, 0u);
        if (yy >= 0 && yy < HP && xx >= 0 && xx < WP)
            v = *reinterpret_cast<const uint4*>(
                reinterpret_cast<const short*>(y64) + (((size_t)b*HP + yy)*WP + xx)*64 + sub*8);
        *reinterpret_cast<uint4*>(&sin_[pix*72 + sub*8]) = v;
    }
    __syncthreads();

    const int wv = tid >> 6;
    const int lane = tid & 63;
    const int n16 = lane & 15;
    const int q = lane >> 4;

    f32x4 acc[4];
    {
        float bv = (n16 < 12) ? b4[n16] : 0.f;
        #pragma unroll
        for (int i = 0; i < 4; ++i) acc[i] = {bv, bv, bv, bv};
    }

    for (int ky = 0; ky < 3; ++ky) {
        for (int kx = 0; kx < 3; ++kx) {
            const int tap = ky*3 + kx;
            short8 bf0 = *reinterpret_cast<const short8*>(w4b + ((tap*2 + 0)*16 + n16)*32 + q*8);
            short8 bf1 = *reinterpret_cast<const short8*>(w4b + ((tap*2 + 1)*16 + n16)*32 + q*8);
            #pragma unroll
            for (int i = 0; i < 4; ++i) {
                int pix = (wv*4 + i + ky)*18 + (n16 + kx);
                short8 a0 = *reinterpret_cast<const short8*>(&sin_[pix*72 + q*8]);
                short8 a1 = *reinterpret_cast<const short8*>(&sin_[pix*72 + 32 + q*8]);
                acc[i] = __builtin_amdgcn_mfma_f32_16x16x32_bf16(a0, bf0, acc[i], 0, 0, 0);
                acc[i] = __builtin_amdgcn_mfma_f32_16x16x32_bf16(a1, bf1, acc[i], 0, 0, 0);
            }
        }
    }

    if (n16 < 12) {
        const int co = n16 >> 2, sy = (n16 >> 1) & 1, sx = n16 & 1;
        #pragma unroll
        for (int i = 0; i < 4; ++i) {
            int yy = y0 + wv*4 + i;
            if (yy >= HIN) continue;
            #pragma unroll
            for (int r = 0; r < 4; ++r) {
                int xx = x0 + q*4 + r;
                if (xx < WIN_)
                    out[((size_t)(b*3 + co)*720 + yy*2 + sy)*1280 + xx*2 + sx]
                        = acc[i][r] + c_mean[co];
            }
        }
    }
}

extern "C" void kernel_launch(void* const* d_in, const int* in_sizes, int n_in,
                              void* d_out, int out_size, void* d_ws, size_t ws_size,
                              hipStream_t stream) {
    const float* x  = (const float*)d_in[0];
    const float* w1 = (const float*)d_in[1];
    const float* b1 = (const float*)d_in[2];
    const float* w2 = (const float*)d_in[3];
    const float* b2 = (const float*)d_in[4];
    const float* wk = (const float*)d_in[5];
    const float* bk = (const float*)d_in[6];
    const float* wb = (const float*)d_in[7];
    const float* bb = (const float*)d_in[8];
    const float* w3 = (const float*)d_in[9];
    const float* b3 = (const float*)d_in[10];
    const float* w4 = (const float*)d_in[11];
    const float* b4 = (const float*)d_in[12];
    float* out = (float*)d_out;

    if (ws_size < WS_NEED) return;

    char* ws = (char*)d_ws;
    short* feat2 = (short*)(ws + OFF_FEAT2);
    float* kb    = (float*)(ws + OFF_KB);
    __hip_bfloat16* y32 = (__hip_bfloat16*)(ws + OFF_Y32);
    __hip_bfloat16* y64 = (__hip_bfloat16*)(ws + OFF_Y64);
    float* w1t = (float*)(ws + OFF_W1T);
    short* w2b = (short*)(ws + OFF_W2B);
    short* wkb = (short*)(ws + OFF_WKB);
    short* w3b = (short*)(ws + OFF_W3B);
    short* w4b = (short*)(ws + OFF_W4B);

    k_prep <<<2016, 256, 0, stream>>>(w1, w1t, w2, w2b, wk, wb, wkb, w3, w3b, w4, w4b);
    k_head <<<BP/16, 256, 0, stream>>>(x, w1t, b1, w2b, b2, feat2);
    k_gemm <<<dim3(150, 7), 256, 0, stream>>>(feat2, wkb, bk, bb, kb);
    k_apply<<<BP, 256, 0, stream>>>(x, kb, y32);
    k_conv3<<<dim3(41, 23, 4), 256, 0, stream>>>(y32, w3b, b3, y64);
    k_conv4<<<dim3(40, 23, 4), 256, 0, stream>>>(y64, w4b, b4, out);
}

// Round 4
// 521.995 us; speedup vs baseline: 6.8431x; 1.2765x over previous
//
#include <hip/hip_runtime.h>
#include <hip/hip_bf16.h>

#define GH 52
#define GW 92
#define BP 19136
#define HP 364
#define WP 644
#define HIN 360
#define WIN_ 640

typedef __attribute__((ext_vector_type(8))) short short8;
typedef __attribute__((ext_vector_type(4))) float f32x4;

__device__ __constant__ float c_mean[3] = {114.444f, 111.4605f, 103.02f};

// workspace layout (bytes)
#define OFF_FEAT1 0ULL            // bf16 [25pos][BP][64c] (61.2 MB) -- dead after conv2
#define OFF_FEAT2 61235200ULL     // bf16 [9po][BP][64oc]  (22.0 MB) -- dead after gemm
#define OFF_KB    83279872ULL     // fp32 BP x 896 (68.6 MB) -- dead after apply
#define OFF_Y64   0ULL            // bf16 NHWC 4x364x644x64 (120.0 MB) -- aliases feat1/feat2/kb
#define OFF_Y32   151863296ULL    // bf16 NHWC 4x364x644x32 (60.0 MB)
#define OFF_BMG   211869696ULL    // fp32 merged bias [896]
#define OFF_W1T   211873280ULL    // fp32 27x64
#define OFF_W2B   211880192ULL    // bf16 [9tap][64oc][64c]
#define OFF_WKB   211953920ULL    // bf16 [896n][9po*64f] (K reordered po*64+f)
#define OFF_W3B   212986112ULL    // bf16 [25tap][64oc][32c]
#define OFF_W4B   213088512ULL    // bf16 [9tap][2kh][16n][32c]
#define WS_NEED   213106944ULL

static __device__ __forceinline__ short bf16bits(float v) {
    __hip_bfloat16 h = __float2bfloat16(v);
    return *reinterpret_cast<short*>(&h);
}

// ---------------- prep: weight repacks + merged bias --------------------------------------
__global__ __launch_bounds__(256) void k_prep(
    const float* __restrict__ w1, float* __restrict__ w1t,
    const float* __restrict__ w2, short* __restrict__ w2b,
    const float* __restrict__ wk, const float* __restrict__ wb, short* __restrict__ wkb,
    const float* __restrict__ bk, const float* __restrict__ bb, float* __restrict__ bmg,
    const float* __restrict__ w3, short* __restrict__ w3b,
    const float* __restrict__ w4, short* __restrict__ w4b)
{
    int i = blockIdx.x * 256 + threadIdx.x;
    if (i < 1728) { int oc = i / 27, k = i % 27; w1t[k*64 + oc] = w1[i]; }
    if (i < 896)  { bmg[i] = (i < 864) ? bk[i] : bb[i - 864]; }
    if (i < 36864) {
        // i = (tap*64 + oc)*64 + c ; w2 layout [oc][c][3][3]
        int c = i & 63; int rest = i >> 6; int oc = rest & 63; int tap = rest >> 6;
        int ky = tap / 3, kx = tap % 3;
        w2b[i] = bf16bits(w2[((oc*64 + c)*3 + ky)*3 + kx]);
    }
    if (i < 516096) {
        // i = n*576 + po*64 + f ; source k-index = f*9 + po
        int n = i / 576, r = i % 576;
        int po = r >> 6, f = r & 63;
        int ks = f*9 + po;
        float v = (n < 864) ? wk[n*576 + ks] : wb[(n - 864)*576 + ks];
        wkb[i] = bf16bits(v);
    }
    if (i < 51200) {
        int c = i & 31; int rest = i >> 5; int oc = rest & 63; int tap = rest >> 6;
        int ky = tap / 5, kx = tap % 5;
        w3b[i] = bf16bits(w3[((oc*32 + c)*5 + ky)*5 + kx]);
    }
    if (i < 9216) {
        int c = i & 31; int rest = i >> 5; int n = rest & 15; rest >>= 4;
        int kh = rest & 1; int tap = rest >> 1;
        int ky = tap / 3, kx = tap % 3;
        float v = 0.f;
        if (n < 12) v = w4[((n*64 + kh*32 + c)*3 + ky)*3 + kx];
        w4b[i] = bf16bits(v);
    }
}

// ---------------- conv1: patch extract + 3->64 3x3 VALID (7->5) -> feat1 [pos][patch][64c] -
__global__ __launch_bounds__(256) void k_conv1(
    const float* __restrict__ x, const float* __restrict__ w1t, const float* __restrict__ b1,
    short* __restrict__ feat1)
{
    __shared__ float sp[16][148];   // 9.5 KB
    const int tid = threadIdx.x;
    const int p0 = blockIdx.x * 16;

    for (int t = tid; t < 16*147; t += 256) {
        int p = t / 147, r = t % 147;
        int c = r / 49, rr = r % 49;
        int i = rr / 7, j = rr % 7;
        int pg = p0 + p;
        int b = pg / (GH*GW), rem = pg % (GH*GW);
        int gy = rem / GW, gx = rem % GW;
        int yy = gy*7 + i, xx = gx*7 + j;
        float v = 0.f;
        if (yy < HIN && xx < WIN_) v = x[((b*3 + c)*HIN + yy)*WIN_ + xx] - c_mean[c];
        sp[p][r] = v;
    }
    __syncthreads();

    // tasks: 25pos x 16p x 8ocg ; consecutive tid -> (ocg,p) fastest => coalesced stores
    for (int t = tid; t < 3200; t += 256) {
        int ocg = t & 7, p = (t >> 3) & 15, pos = t >> 7;
        int pi = pos / 5, pj = pos % 5;
        float acc[8];
        #pragma unroll
        for (int u = 0; u < 8; ++u) acc[u] = b1[ocg*8 + u];
        #pragma unroll
        for (int c = 0; c < 3; ++c)
            #pragma unroll
            for (int ki = 0; ki < 3; ++ki)
                #pragma unroll
                for (int kj = 0; kj < 3; ++kj) {
                    float fv = sp[p][c*49 + (pi+ki)*7 + (pj+kj)];
                    const float* wr = w1t + (c*9 + ki*3 + kj)*64 + ocg*8;
                    const float4 wa = *reinterpret_cast<const float4*>(wr);
                    const float4 wb4 = *reinterpret_cast<const float4*>(wr + 4);
                    acc[0] += fv*wa.x;  acc[1] += fv*wa.y;  acc[2] += fv*wa.z;  acc[3] += fv*wa.w;
                    acc[4] += fv*wb4.x; acc[5] += fv*wb4.y; acc[6] += fv*wb4.z; acc[7] += fv*wb4.w;
                }
        short8 pack;
        #pragma unroll
        for (int u = 0; u < 8; ++u) pack[u] = bf16bits(fmaxf(acc[u], 0.f));
        *reinterpret_cast<short8*>(feat1 + (size_t)pos*(BP*64) + (size_t)(p0 + p)*64 + ocg*8) = pack;
    }
}

// ---------------- conv2: per-tap MFMA, LDS-free. D[m=oc][n=patch] -> feat2 [po][patch][oc] -
__global__ __launch_bounds__(256) void k_conv2(
    const short* __restrict__ feat1, const short* __restrict__ w2b,
    const float* __restrict__ b2, short* __restrict__ feat2)
{
    const int tid = threadIdx.x;
    const int wv = tid >> 6, lane = tid & 63;
    const int n16 = lane & 15, q = lane >> 4;
    const int po = blockIdx.y;
    const int pi = po / 3, pj = po % 3;
    const int p0 = blockIdx.x * 128 + wv * 32;   // this wave: 32 patches (2 n-tiles)

    f32x4 acc[4][2];
    #pragma unroll
    for (int j = 0; j < 4; ++j) {
        float4 bj = *reinterpret_cast<const float4*>(b2 + j*16 + q*4);
        f32x4 bi = {bj.x, bj.y, bj.z, bj.w};
        acc[j][0] = bi; acc[j][1] = bi;
    }

    for (int ki = 0; ki < 3; ++ki)
        for (int kj = 0; kj < 3; ++kj) {
            const int tap = ki*3 + kj;
            const size_t base = (size_t)((pi+ki)*5 + (pj+kj)) * (BP*64);
            #pragma unroll
            for (int ks = 0; ks < 2; ++ks) {
                short8 af[4];
                #pragma unroll
                for (int j = 0; j < 4; ++j)
                    af[j] = *reinterpret_cast<const short8*>(w2b + (tap*64 + j*16 + n16)*64 + ks*32 + q*8);
                short8 bf[2];
                #pragma unroll
                for (int nt = 0; nt < 2; ++nt) {
                    int pr = p0 + nt*16 + n16; pr = (pr < BP) ? pr : (BP-1);
                    bf[nt] = *reinterpret_cast<const short8*>(feat1 + base + (size_t)pr*64 + ks*32 + q*8);
                }
                #pragma unroll
                for (int j = 0; j < 4; ++j)
                    #pragma unroll
                    for (int nt = 0; nt < 2; ++nt)
                        acc[j][nt] = __builtin_amdgcn_mfma_f32_16x16x32_bf16(af[j], bf[nt], acc[j][nt], 0, 0, 0);
            }
        }

    // store: lane holds oc = j*16 + q*4 + r for patch = p0+nt*16+n16 -> 8B packed, relu
    #pragma unroll
    for (int nt = 0; nt < 2; ++nt) {
        int pr = p0 + nt*16 + n16;
        if (pr >= BP) continue;
        #pragma unroll
        for (int j = 0; j < 4; ++j) {
            short4 pk;
            pk.x = bf16bits(fmaxf(acc[j][nt][0], 0.f));
            pk.y = bf16bits(fmaxf(acc[j][nt][1], 0.f));
            pk.z = bf16bits(fmaxf(acc[j][nt][2], 0.f));
            pk.w = bf16bits(fmaxf(acc[j][nt][3], 0.f));
            *reinterpret_cast<short4*>(feat2 + (size_t)po*(BP*64) + (size_t)pr*64 + j*16 + q*4) = pk;
        }
    }
}

// ---------------- GEMM MFMA: kb[p][n] = feat2 @ wkb^T + bias ; A=wkb rows, B=patch cols ----
__global__ __launch_bounds__(256) void k_gemm(
    const short* __restrict__ feat2, const short* __restrict__ wkb,
    const float* __restrict__ bmg, float* __restrict__ kb)
{
    __shared__ __align__(16) short As[128*40];   // wkb rows (n-dim)
    __shared__ __align__(16) short Bs[128*40];   // patch rows
    const int tid = threadIdx.x;
    const int p0 = blockIdx.x * 128, n0 = blockIdx.y * 128;
    const int wv = tid >> 6, lane = tid & 63;
    const int n16 = lane & 15, q = lane >> 4;
    const int wm = wv & 1, wn = wv >> 1;

    f32x4 acc[4][4] = {};

    for (int k0 = 0; k0 < 576; k0 += 32) {
        const int po = k0 >> 6, cb = k0 & 63;
        for (int t = tid; t < 512; t += 256) {
            int row = t >> 2, seg = t & 3;
            uint4 a = *reinterpret_cast<const uint4*>(wkb + (size_t)(n0 + row)*576 + k0 + seg*8);
            int pr = p0 + row; pr = (pr < BP) ? pr : (BP-1);
            uint4 b = *reinterpret_cast<const uint4*>(feat2 + (size_t)po*(BP*64) + (size_t)pr*64 + cb + seg*8);
            *reinterpret_cast<uint4*>(&As[row*40 + seg*8]) = a;
            *reinterpret_cast<uint4*>(&Bs[row*40 + seg*8]) = b;
        }
        __syncthreads();
        short8 af[4], bf[4];
        #pragma unroll
        for (int mt = 0; mt < 4; ++mt)
            af[mt] = *reinterpret_cast<const short8*>(&As[(wm*64 + mt*16 + n16)*40 + q*8]);
        #pragma unroll
        for (int nt = 0; nt < 4; ++nt)
            bf[nt] = *reinterpret_cast<const short8*>(&Bs[(wn*64 + nt*16 + n16)*40 + q*8]);
        #pragma unroll
        for (int mt = 0; mt < 4; ++mt)
            #pragma unroll
            for (int nt = 0; nt < 4; ++nt)
                acc[mt][nt] = __builtin_amdgcn_mfma_f32_16x16x32_bf16(af[mt], bf[nt], acc[mt][nt], 0, 0, 0);
        __syncthreads();
    }

    // D[m=wkb n-dim][n=patch]: lane n16=patch, q*4+r = n-dim -> float4 stores along kb row
    #pragma unroll
    for (int nt = 0; nt < 4; ++nt) {
        int pr = p0 + wn*64 + nt*16 + n16;
        if (pr >= BP) continue;
        #pragma unroll
        for (int mt = 0; mt < 4; ++mt) {
            int nb = n0 + wm*64 + mt*16 + q*4;
            float4 bs = *reinterpret_cast<const float4*>(bmg + nb);
            float4 v;
            v.x = acc[mt][nt][0] + bs.x;
            v.y = acc[mt][nt][1] + bs.y;
            v.z = acc[mt][nt][2] + bs.z;
            v.w = acc[mt][nt][3] + bs.w;
            *reinterpret_cast<float4*>(kb + (size_t)pr*896 + nb) = v;
        }
    }
}

// ---------------- apply predicted 3x3x3->32 kernel per patch -> y32 NHWC bf16 --------------
__global__ __launch_bounds__(256) void k_apply(
    const float* __restrict__ x, const float* __restrict__ kb, __hip_bfloat16* __restrict__ y32)
{
    __shared__ float pp[3][9][9];
    __shared__ __align__(16) float kl[27][32];
    __shared__ float bl[32];
    const int p = blockIdx.x;
    const int tid = threadIdx.x;
    const int b = p / (GH*GW), rem = p % (GH*GW);
    const int gy = rem / GW, gx = rem % GW;

    for (int t = tid; t < 243; t += 256) ((float*)pp)[t] = 0.f;
    __syncthreads();
    for (int t = tid; t < 147; t += 256) {
        int c = t / 49, r = t % 49, i = r / 7, j = r % 7;
        int yy = gy*7 + i, xx = gx*7 + j;
        float v = 0.f;
        if (yy < HIN && xx < WIN_) v = x[((b*3 + c)*HIN + yy)*WIN_ + xx] - c_mean[c];
        pp[c][i+1][j+1] = v;
    }
    for (int t = tid; t < 864; t += 256) {
        int f = t / 27, k = t % 27;
        kl[k][f] = kb[(size_t)p*896 + f*27 + k];
    }
    if (tid < 32) bl[tid] = kb[(size_t)p*896 + 864 + tid];
    __syncthreads();

    if (tid < 196) {
        int pos = tid % 49, fg = tid / 49;
        int h = pos / 7, w = pos % 7;
        float win[27];
        #pragma unroll
        for (int c = 0; c < 3; ++c)
            #pragma unroll
            for (int i = 0; i < 3; ++i)
                #pragma unroll
                for (int j = 0; j < 3; ++j)
                    win[c*9 + i*3 + j] = pp[c][h+i][w+j];
        float acc[8];
        #pragma unroll
        for (int u = 0; u < 8; ++u) acc[u] = bl[fg*8 + u];
        #pragma unroll
        for (int k = 0; k < 27; ++k) {
            const float4 wa = *reinterpret_cast<const float4*>(&kl[k][fg*8]);
            const float4 wb4 = *reinterpret_cast<const float4*>(&kl[k][fg*8 + 4]);
            float v = win[k];
            acc[0] += v*wa.x;  acc[1] += v*wa.y;  acc[2] += v*wa.z;  acc[3] += v*wa.w;
            acc[4] += v*wb4.x; acc[5] += v*wb4.y; acc[6] += v*wb4.z; acc[7] += v*wb4.w;
        }
        int yy = gy*7 + h, xx = gx*7 + w;
        short8 pack;
        #pragma unroll
        for (int u = 0; u < 8; ++u) pack[u] = bf16bits(acc[u]);
        *reinterpret_cast<short8*>(
            reinterpret_cast<short*>(y32) + (((size_t)b*HP + yy)*WP + xx)*32 + fg*8) = pack;
    }
}

// ---------------- conv3 MFMA: NHWC 32->64, 5x5 pad2 + relu. D[m=oc][n=px] -----------------
__global__ __launch_bounds__(256) void k_conv3(
    const __hip_bfloat16* __restrict__ y32, const short* __restrict__ w3b,
    const float* __restrict__ b3, __hip_bfloat16* __restrict__ y64)
{
    __shared__ __align__(16) short sin_[20*20*40];   // 32 KB
    const int tid = threadIdx.x;
    const int x0 = blockIdx.x * 16, y0 = blockIdx.y * 16, b = blockIdx.z;

    for (int t = tid; t < 1600; t += 256) {
        int pix = t >> 2, q4 = t & 3;
        int iy = pix / 20, ix = pix % 20;
        int yy = y0 + iy - 2, xx = x0 + ix - 2;
        uint4 v = make_uint4(0u, 0u, 0u, 0u);
        if (yy >= 0 && yy < HP && xx >= 0 && xx < WP)
            v = *reinterpret_cast<const uint4*>(
                reinterpret_cast<const short*>(y32) + (((size_t)b*HP + yy)*WP + xx)*32 + q4*8);
        *reinterpret_cast<uint4*>(&sin_[pix*40 + q4*8]) = v;
    }
    __syncthreads();

    const int wv = tid >> 6;
    const int lane = tid & 63;
    const int n16 = lane & 15;
    const int q = lane >> 4;

    f32x4 acc[4][4];
    #pragma unroll
    for (int j = 0; j < 4; ++j) {
        float4 bj = *reinterpret_cast<const float4*>(b3 + j*16 + q*4);
        f32x4 bi = {bj.x, bj.y, bj.z, bj.w};
        #pragma unroll
        for (int i = 0; i < 4; ++i) acc[i][j] = bi;
    }

    for (int ky = 0; ky < 5; ++ky) {
        for (int kx = 0; kx < 5; ++kx) {
            const int tap = ky*5 + kx;
            short8 afw[4];
            #pragma unroll
            for (int j = 0; j < 4; ++j)
                afw[j] = *reinterpret_cast<const short8*>(w3b + (tap*64 + j*16 + n16)*32 + q*8);
            short8 bfa[4];
            #pragma unroll
            for (int i = 0; i < 4; ++i) {
                int pix = (wv*4 + i + ky)*20 + (n16 + kx);
                bfa[i] = *reinterpret_cast<const short8*>(&sin_[pix*40 + q*8]);
            }
            #pragma unroll
            for (int i = 0; i < 4; ++i)
                #pragma unroll
                for (int j = 0; j < 4; ++j)
                    acc[i][j] = __builtin_amdgcn_mfma_f32_16x16x32_bf16(afw[j], bfa[i], acc[i][j], 0, 0, 0);
        }
    }

    // lane: pixel-x = x0+n16, oc = j*16+q*4+r -> 8B packed stores
    const int xx = x0 + n16;
    if (xx < WP) {
        #pragma unroll
        for (int i = 0; i < 4; ++i) {
            int yy = y0 + wv*4 + i;
            if (yy >= HP) continue;
            short* dst = reinterpret_cast<short*>(y64) + (((size_t)b*HP + yy)*WP + xx)*64;
            #pragma unroll
            for (int j = 0; j < 4; ++j) {
                short4 pk;
                pk.x = bf16bits(fmaxf(acc[i][j][0], 0.f));
                pk.y = bf16bits(fmaxf(acc[i][j][1], 0.f));
                pk.z = bf16bits(fmaxf(acc[i][j][2], 0.f));
                pk.w = bf16bits(fmaxf(acc[i][j][3], 0.f));
                *reinterpret_cast<short4*>(dst + j*16 + q*4) = pk;
            }
        }
    }
}

// ---------------- conv4 MFMA: 64->12 3x3 pad1 + pixel-shuffle + mean. D[m=ch][n=px] --------
__global__ __launch_bounds__(256) void k_conv4(
    const __hip_bfloat16* __restrict__ y64, const short* __restrict__ w4b,
    const float* __restrict__ b4, float* __restrict__ out)
{
    __shared__ __align__(16) short sin_[18*18*72];
    const int tid = threadIdx.x;
    const int x0 = blockIdx.x * 16, y0 = blockIdx.y * 16, b = blockIdx.z;

    for (int t = tid; t < 2592; t += 256) {
        int pix = t >> 3, sub = t & 7;
        int iy = pix / 18, ix = pix % 18;
        int yy = y0 + iy - 1, xx = x0 + ix - 1;
        uint4 v = make_uint4(0u, 0u, 0u, 0u);
        if (yy >= 0 && yy < HP && xx >= 0 && xx < WP)
            v = *reinterpret_cast<const uint4*>(
                reinterpret_cast<const short*>(y64) + (((size_t)b*HP + yy)*WP + xx)*64 + sub*8);
        *reinterpret_cast<uint4*>(&sin_[pix*72 + sub*8]) = v;
    }
    __syncthreads();

    const int wv = tid >> 6;
    const int lane = tid & 63;
    const int n16 = lane & 15;
    const int q = lane >> 4;

    f32x4 acc[4];
    {
        f32x4 bi = {0.f, 0.f, 0.f, 0.f};
        if (q < 3) {
            float4 bq = *reinterpret_cast<const float4*>(b4 + q*4);
            bi = {bq.x, bq.y, bq.z, bq.w};
        }
        #pragma unroll
        for (int i = 0; i < 4; ++i) acc[i] = bi;
    }

    for (int ky = 0; ky < 3; ++ky) {
        for (int kx = 0; kx < 3; ++kx) {
            const int tap = ky*3 + kx;
            short8 af0 = *reinterpret_cast<const short8*>(w4b + ((tap*2 + 0)*16 + n16)*32 + q*8);
            short8 af1 = *reinterpret_cast<const short8*>(w4b + ((tap*2 + 1)*16 + n16)*32 + q*8);
            #pragma unroll
            for (int i = 0; i < 4; ++i) {
                int pix = (wv*4 + i + ky)*18 + (n16 + kx);
                short8 a0 = *reinterpret_cast<const short8*>(&sin_[pix*72 + q*8]);
                short8 a1 = *reinterpret_cast<const short8*>(&sin_[pix*72 + 32 + q*8]);
                acc[i] = __builtin_amdgcn_mfma_f32_16x16x32_bf16(af0, a0, acc[i], 0, 0, 0);
                acc[i] = __builtin_amdgcn_mfma_f32_16x16x32_bf16(af1, a1, acc[i], 0, 0, 0);
            }
        }
    }

    // lane: pixel-x = x0+n16 (<640 always), ch = q*4+r ; q=co (q<3), r=(sy,sx) quad
    if (q < 3) {
        const int xx = x0 + n16;
        const float m = c_mean[q];
        #pragma unroll
        for (int i = 0; i < 4; ++i) {
            int yy = y0 + wv*4 + i;
            if (yy >= HIN) continue;
            size_t r0 = ((size_t)(b*3 + q)*720 + yy*2)*1280 + xx*2;
            float2 s0 = {acc[i][0] + m, acc[i][1] + m};
            float2 s1 = {acc[i][2] + m, acc[i][3] + m};
            *reinterpret_cast<float2*>(out + r0) = s0;
            *reinterpret_cast<float2*>(out + r0 + 1280) = s1;
        }
    }
}

extern "C" void kernel_launch(void* const* d_in, const int* in_sizes, int n_in,
                              void* d_out, int out_size, void* d_ws, size_t ws_size,
                              hipStream_t stream) {
    const float* x  = (const float*)d_in[0];
    const float* w1 = (const float*)d_in[1];
    const float* b1 = (const float*)d_in[2];
    const float* w2 = (const float*)d_in[3];
    const float* b2 = (const float*)d_in[4];
    const float* wk = (const float*)d_in[5];
    const float* bk = (const float*)d_in[6];
    const float* wb = (const float*)d_in[7];
    const float* bb = (const float*)d_in[8];
    const float* w3 = (const float*)d_in[9];
    const float* b3 = (const float*)d_in[10];
    const float* w4 = (const float*)d_in[11];
    const float* b4 = (const float*)d_in[12];
    float* out = (float*)d_out;

    if (ws_size < WS_NEED) return;

    char* ws = (char*)d_ws;
    short* feat1 = (short*)(ws + OFF_FEAT1);
    short* feat2 = (short*)(ws + OFF_FEAT2);
    float* kb    = (float*)(ws + OFF_KB);
    __hip_bfloat16* y32 = (__hip_bfloat16*)(ws + OFF_Y32);
    __hip_bfloat16* y64 = (__hip_bfloat16*)(ws + OFF_Y64);
    float* bmg = (float*)(ws + OFF_BMG);
    float* w1t = (float*)(ws + OFF_W1T);
    short* w2b = (short*)(ws + OFF_W2B);
    short* wkb = (short*)(ws + OFF_WKB);
    short* w3b = (short*)(ws + OFF_W3B);
    short* w4b = (short*)(ws + OFF_W4B);

    k_prep <<<2016, 256, 0, stream>>>(w1, w1t, w2, w2b, wk, wb, wkb, bk, bb, bmg, w3, w3b, w4, w4b);
    k_conv1<<<BP/16, 256, 0, stream>>>(x, w1t, b1, feat1);
    k_conv2<<<dim3(150, 9), 256, 0, stream>>>(feat1, w2b, b2, feat2);
    k_gemm <<<dim3(150, 7), 256, 0, stream>>>(feat2, wkb, bmg, kb);
    k_apply<<<BP, 256, 0, stream>>>(x, kb, y32);
    k_conv3<<<dim3(41, 23, 4), 256, 0, stream>>>(y32, w3b, b3, y64);
    k_conv4<<<dim3(40, 23, 4), 256, 0, stream>>>(y64, w4b, b4, out);
}